// Round 7
// baseline (44.077 us; speedup 1.0000x reference)
//
#include <hip/hip_runtime.h>
#include <math.h>

#define NN 2048
#define CC 128
#define ROWS 16
#define EPSF 1e-16f

typedef __attribute__((ext_vector_type(8))) short bf16x8;
typedef __attribute__((ext_vector_type(4))) float f32x4;

__device__ __forceinline__ float softplusf(float x) {
  return fmaxf(x, 0.0f) + log1pf(__expf(-fabsf(x)));
}

union U8 { uint u[4]; bf16x8 v; };

// split 8 fp32 into bf16 hi (truncate) + bf16 lo (residual, truncate),
// packed for MFMA; also accumulate sum of squares of the originals.
__device__ __forceinline__ void split8(float4 a, float4 b, bf16x8& hi,
                                       bf16x8& lo, float& sq) {
  float f[8] = {a.x, a.y, a.z, a.w, b.x, b.y, b.z, b.w};
  U8 H, L;
#pragma unroll
  for (int i = 0; i < 4; ++i) {
    float f0 = f[2 * i], f1 = f[2 * i + 1];
    sq += f0 * f0;
    sq += f1 * f1;
    uint u0 = __float_as_uint(f0), u1 = __float_as_uint(f1);
    uint m0 = u0 & 0xffff0000u, m1 = u1 & 0xffff0000u;
    float r0 = f0 - __uint_as_float(m0);
    float r1 = f1 - __uint_as_float(m1);
    H.u[i] = (u0 >> 16) | m1;
    L.u[i] = (__float_as_uint(r0) >> 16) | (__float_as_uint(r1) & 0xffff0000u);
  }
  hi = H.v;
  lo = L.v;
}

// ---------------- prep: split M and k into frag-ordered bf16 hi/lo, ----
// ---------------- row norms, and per-row activation scalars ------------
__global__ __launch_bounds__(256) void ntm_prep_kernel(
    const float* __restrict__ kptr, const float* __restrict__ beta_,
    const float* __restrict__ g_, const float* __restrict__ s_,
    const float* __restrict__ gamma_, const float* __restrict__ M,
    bf16x8* __restrict__ Mhf, bf16x8* __restrict__ Mlf,
    bf16x8* __restrict__ Khf, bf16x8* __restrict__ Klf,
    float* __restrict__ imn, float* __restrict__ zb, float* __restrict__ gvv,
    float* __restrict__ gmv, float* __restrict__ s0a, float* __restrict__ s1a,
    float* __restrict__ s2a) {
  const int bid = blockIdx.x;
  const int t = threadIdx.x;
  if (bid < 96) {
    const int lane = t & 63;
    const int wv = t >> 6;
    const int l15 = lane & 15;
    const int lg = lane >> 4;
    const bool isM = bid < 32;
    const int grp = (isM ? bid : bid - 32) * 4 + wv;  // M: 0..127, K: 0..255
    const float* src = (isM ? M : kptr) + (grp * 16 + l15) * CC + lg * 8;
    bf16x8* dh = (isM ? Mhf : Khf) + (grp * 4) * 64 + lane;
    bf16x8* dl = (isM ? Mlf : Klf) + (grp * 4) * 64 + lane;
    float sq = 0.f;
#pragma unroll
    for (int ks = 0; ks < 4; ++ks) {
      float4 a0 = *(const float4*)(src + ks * 32);
      float4 a1 = *(const float4*)(src + ks * 32 + 4);
      bf16x8 h, l;
      split8(a0, a1, h, l, sq);
      dh[ks * 64] = h;
      dl[ks * 64] = l;
    }
    sq += __shfl_xor(sq, 16, 64);
    sq += __shfl_xor(sq, 32, 64);
    if (lg == 0) {
      const int row = grp * 16 + l15;
      if (isM) {
        imn[row] = 1.0f / sqrtf(sq);
      } else {
        zb[row] = softplusf(beta_[row]) / sqrtf(sq);  // beta * (1/||k||)
      }
    }
  } else {
    const int r = (bid - 96) * 256 + t;  // 0..4095
    gvv[r] = 1.0f / (1.0f + __expf(-g_[r]));
    gmv[r] = 1.0f + softplusf(gamma_[r]);
    float sh0 = s_[3 * r], sh1 = s_[3 * r + 1], sh2 = s_[3 * r + 2];
    float shm = fmaxf(sh0, fmaxf(sh1, sh2));
    float e0 = __expf(sh0 - shm), e1 = __expf(sh1 - shm), e2 = __expf(sh2 - shm);
    float sden = 1.0f / (e0 + e1 + e2);
    s0a[r] = e0 * sden;
    s1a[r] = e1 * sden;
    s2a[r] = e2 * sden;
  }
}

// ---------------- main: MFMA matmul + fused softmax/gate/conv/sharpen ----
// __launch_bounds__(1024, 4): 16-wave block = 4 waves/EU -> VGPR cap 128.
// Grid is 1 block/CU, so there is no second block to save registers for.
__global__ __launch_bounds__(1024, 4) void ntm_main_kernel(
    const float* __restrict__ w_prev, const bf16x8* __restrict__ Mhf,
    const bf16x8* __restrict__ Mlf, const bf16x8* __restrict__ Khf,
    const bf16x8* __restrict__ Klf, const float* __restrict__ imn,
    const float* __restrict__ zb, const float* __restrict__ gvv,
    const float* __restrict__ gmv, const float* __restrict__ s0a,
    const float* __restrict__ s1a, const float* __restrict__ s2a,
    float* __restrict__ out) {
  __shared__ float red[ROWS][16];       // [row][wave] partial sums
  __shared__ float edges[ROWS][16][2];  // [row][wave][first,last] w_g

  const int t = threadIdx.x;
  const int lane = t & 63;
  const int w = __builtin_amdgcn_readfirstlane(t >> 6);  // 0..15
  const int l15 = lane & 15;
  const int lg = lane >> 4;  // 0..3
  const int bg = blockIdx.x;
  const int b0 = bg * ROWS;

  // ---- phase 1: software-pipelined MFMA over 8 half-steps ----
  // half-step h: ks = h>>1, tiles tt = (h&1)*4 .. +3
  // frag address (bf16x8 units): Mhf + 2048*w + 256*tt + 64*ks + lane
  const bf16x8* __restrict__ MhB = Mhf + 2048 * w + lane;
  const bf16x8* __restrict__ MlB = Mlf + 2048 * w + lane;
  const bf16x8* __restrict__ KhB = Khf + 256 * bg + lane;
  const bf16x8* __restrict__ KlB = Klf + 256 * bg + lane;

  f32x4 accT[8];
#pragma unroll
  for (int tt = 0; tt < 8; ++tt) accT[tt] = (f32x4){0.f, 0.f, 0.f, 0.f};

  bf16x8 bh0[4], bl0[4], bh1[4], bl1[4];
  bf16x8 ah0, al0, ah1, al1;

#define LOADB(BH, BL, H)                                      \
  {                                                           \
    const int ks_ = (H) >> 1, hf_ = (H)&1;                    \
    _Pragma("unroll") for (int j = 0; j < 4; ++j) {           \
      BH[j] = MhB[256 * (hf_ * 4 + j) + 64 * ks_];            \
      BL[j] = MlB[256 * (hf_ * 4 + j) + 64 * ks_];            \
    }                                                         \
  }
#define LOADA(AH, AL, KS)                                     \
  AH = KhB[64 * (KS)];                                        \
  AL = KlB[64 * (KS)];
#define DOMFMA(BH, BL, AH, AL, H)                                              \
  {                                                                            \
    const int hf_ = (H)&1;                                                     \
    _Pragma("unroll") for (int j = 0; j < 4; ++j) {                            \
      accT[hf_ * 4 + j] = __builtin_amdgcn_mfma_f32_16x16x32_bf16(             \
          AH, BH[j], accT[hf_ * 4 + j], 0, 0, 0);                              \
      accT[hf_ * 4 + j] = __builtin_amdgcn_mfma_f32_16x16x32_bf16(             \
          AL, BH[j], accT[hf_ * 4 + j], 0, 0, 0);                              \
      accT[hf_ * 4 + j] = __builtin_amdgcn_mfma_f32_16x16x32_bf16(             \
          AH, BL[j], accT[hf_ * 4 + j], 0, 0, 0);                              \
    }                                                                          \
  }

  LOADB(bh0, bl0, 0);
  LOADA(ah0, al0, 0);
  LOADB(bh1, bl1, 1);
  DOMFMA(bh0, bl0, ah0, al0, 0);  // h=0 (ks0)
  LOADB(bh0, bl0, 2);
  LOADA(ah1, al1, 1);
  DOMFMA(bh1, bl1, ah0, al0, 1);  // h=1 (ks0)
  LOADB(bh1, bl1, 3);
  DOMFMA(bh0, bl0, ah1, al1, 2);  // h=2 (ks1)
  LOADB(bh0, bl0, 4);
  LOADA(ah0, al0, 2);
  DOMFMA(bh1, bl1, ah1, al1, 3);  // h=3 (ks1)
  LOADB(bh1, bl1, 5);
  DOMFMA(bh0, bl0, ah0, al0, 4);  // h=4 (ks2)
  LOADB(bh0, bl0, 6);
  LOADA(ah1, al1, 3);
  DOMFMA(bh1, bl1, ah0, al0, 5);  // h=5 (ks2)
  LOADB(bh1, bl1, 7);
  DOMFMA(bh0, bl0, ah1, al1, 6);  // h=6 (ks3)
  DOMFMA(bh1, bl1, ah1, al1, 7);  // h=7 (ks3)

#undef LOADB
#undef LOADA
#undef DOMFMA
  // D layout: col(n) = 128w + 16tt + l15 ; row(batch) = lg*4 + q

  // ---- T14 prefetch: w_prev + per-row/col scalars, issued before phase 2a,
  // ---- consumed after B1 (latency hides under exp/reduction + MFMA drain) ----
  float wp[4][8];
#pragma unroll
  for (int q = 0; q < 4; ++q) {
    const size_t rbase = (size_t)(b0 + lg * 4 + q) * NN + 128 * w + l15;
#pragma unroll
    for (int tt = 0; tt < 8; ++tt) wp[q][tt] = w_prev[rbase + 16 * tt];
  }
  float imn_t[8];
#pragma unroll
  for (int tt = 0; tt < 8; ++tt) imn_t[tt] = imn[128 * w + 16 * tt + l15];
  float zbv[4], gvq[4];
#pragma unroll
  for (int q = 0; q < 4; ++q) {
    zbv[q] = zb[b0 + lg * 4 + q];
    gvq[q] = gvv[b0 + lg * 4 + q];
  }

  // ---- phase 2a: logits -> exp -> per-wave row sums ----
#pragma unroll
  for (int q = 0; q < 4; ++q) {
    const int rr = lg * 4 + q;
    float rs = 0.f;
#pragma unroll
    for (int tt = 0; tt < 8; ++tt) {
      float e = __expf(accT[tt][q] * imn_t[tt] * zbv[q]);  // |logit| <= ~5
      accT[tt][q] = e;
      rs += e;
    }
    rs += __shfl_xor(rs, 1, 64);
    rs += __shfl_xor(rs, 2, 64);
    rs += __shfl_xor(rs, 4, 64);
    rs += __shfl_xor(rs, 8, 64);
    if (l15 == 0) red[rr][w] = rs;
  }
  __syncthreads();  // B1

  // ---- phase 2b: softmax-normalize, gate with w_prev, write slab edges ----
#pragma unroll
  for (int q = 0; q < 4; ++q) {
    const int rr = lg * 4 + q;
    float4 p0 = *(const float4*)&red[rr][0];
    float4 p1 = *(const float4*)&red[rr][4];
    float4 p2 = *(const float4*)&red[rr][8];
    float4 p3 = *(const float4*)&red[rr][12];
    float tot = (p0.x + p0.y + p0.z + p0.w) + (p1.x + p1.y + p1.z + p1.w) +
                (p2.x + p2.y + p2.z + p2.w) + (p3.x + p3.y + p3.z + p3.w);
    const float gv = gvq[q];
    const float ge = gv / tot;
    const float om = 1.0f - gv;
#pragma unroll
    for (int tt = 0; tt < 8; ++tt) {
      accT[tt][q] = ge * accT[tt][q] + om * wp[q][tt];
    }
    if (l15 == 0) edges[rr][w][0] = accT[0][q];
    if (l15 == 15) edges[rr][w][1] = accT[7][q];
  }
  __syncthreads();  // B2

  // ---- phase 2c: circular conv (in-group shuffles) + sharpen + row sums ----
  const int tm = (lane & 48) | ((lane + 15) & 15);
  const int tp = (lane & 48) | ((lane + 1) & 15);
#pragma unroll
  for (int q = 0; q < 4; ++q) {
    const int rr = lg * 4 + q;
    const float sh0 = s0a[b0 + rr];
    const float sh1 = s1a[b0 + rr];
    const float sh2 = s2a[b0 + rr];
    const float gammav = gmv[b0 + rr];
    const float eL = edges[rr][(w + 15) & 15][1];  // w_g[n-1] at slab start
    const float eR = edges[rr][(w + 1) & 15][0];   // w_g[n+1] at slab end

    float sm[8], sp[8];
#pragma unroll
    for (int tt = 0; tt < 8; ++tt) {
      sm[tt] = __shfl(accT[tt][q], tm, 64);
      sp[tt] = __shfl(accT[tt][q], tp, 64);
    }
    float rs = 0.f;
#pragma unroll
    for (int tt = 0; tt < 8; ++tt) {
      float pv = (l15 == 0) ? ((tt == 0) ? eL : sm[tt - 1]) : sm[tt];
      float nx = (l15 == 15) ? ((tt == 7) ? eR : sp[tt + 1]) : sp[tt];
      float wt = sh0 * pv + sh1 * accT[tt][q] + sh2 * nx;
      float p = __expf(gammav * __logf(wt));  // wt^gamma ; wt>0
      accT[tt][q] = p;
      rs += p;
    }
    rs += __shfl_xor(rs, 1, 64);
    rs += __shfl_xor(rs, 2, 64);
    rs += __shfl_xor(rs, 4, 64);
    rs += __shfl_xor(rs, 8, 64);
    if (l15 == 0) red[rr][w] = rs;
  }
  __syncthreads();  // B3

  // ---- phase 2d: final normalize + store ----
#pragma unroll
  for (int q = 0; q < 4; ++q) {
    const int rr = lg * 4 + q;
    float4 p0 = *(const float4*)&red[rr][0];
    float4 p1 = *(const float4*)&red[rr][4];
    float4 p2 = *(const float4*)&red[rr][8];
    float4 p3 = *(const float4*)&red[rr][12];
    float tot = (p0.x + p0.y + p0.z + p0.w) + (p1.x + p1.y + p1.z + p1.w) +
                (p2.x + p2.y + p2.z + p2.w) + (p3.x + p3.y + p3.z + p3.w);
    const float pinv = 1.0f / (tot + EPSF);
    const size_t rbase = (size_t)(b0 + rr) * NN + 128 * w + l15;
#pragma unroll
    for (int tt = 0; tt < 8; ++tt) {
      out[rbase + 16 * tt] = accT[tt][q] * pinv;
    }
  }
}

// ---------------- fallback (round-4 kernel, no workspace) ----------------
__global__ __launch_bounds__(1024) void ntm_main_fallback(
    const float* __restrict__ kptr, const float* __restrict__ beta_,
    const float* __restrict__ g_, const float* __restrict__ s_,
    const float* __restrict__ gamma_, const float* __restrict__ w_prev,
    const float* __restrict__ Mptr, float* __restrict__ out) {
  __shared__ float red[ROWS][16];
  __shared__ float edges[ROWS][16][2];
  const int t = threadIdx.x;
  const int lane = t & 63;
  const int w = __builtin_amdgcn_readfirstlane(t >> 6);
  const int l15 = lane & 15;
  const int lg = lane >> 4;
  const int b0 = blockIdx.x * ROWS;

  const float* kr = kptr + (b0 + l15) * CC + lg * 8;
  bf16x8 ah[4], al[4];
  float ksq = 0.f;
#pragma unroll
  for (int ks = 0; ks < 4; ++ks) {
    float4 a0 = *(const float4*)(kr + ks * 32);
    float4 a1 = *(const float4*)(kr + ks * 32 + 4);
    split8(a0, a1, ah[ks], al[ks], ksq);
  }
  ksq += __shfl_xor(ksq, 16, 64);
  ksq += __shfl_xor(ksq, 32, 64);
  const float ikn_own = 1.0f / sqrtf(ksq);

  f32x4 accT[8];
  float imn[8];
#pragma unroll
  for (int tt = 0; tt < 8; ++tt) {
    const int n0t = 128 * w + 16 * tt;
    const float* mr = Mptr + (size_t)(n0t + l15) * CC + lg * 8;
    f32x4 acc = {0.f, 0.f, 0.f, 0.f};
    float msq = 0.f;
#pragma unroll
    for (int ks = 0; ks < 4; ++ks) {
      float4 m0 = *(const float4*)(mr + ks * 32);
      float4 m1 = *(const float4*)(mr + ks * 32 + 4);
      bf16x8 bh, bl;
      split8(m0, m1, bh, bl, msq);
      acc = __builtin_amdgcn_mfma_f32_16x16x32_bf16(ah[ks], bh, acc, 0, 0, 0);
      acc = __builtin_amdgcn_mfma_f32_16x16x32_bf16(al[ks], bh, acc, 0, 0, 0);
      acc = __builtin_amdgcn_mfma_f32_16x16x32_bf16(ah[ks], bl, acc, 0, 0, 0);
    }
    msq += __shfl_xor(msq, 16, 64);
    msq += __shfl_xor(msq, 32, 64);
    imn[tt] = 1.0f / sqrtf(msq);
    accT[tt] = acc;
  }

#pragma unroll
  for (int q = 0; q < 4; ++q) {
    const int rr = lg * 4 + q;
    const float zb = softplusf(beta_[b0 + rr]) * __shfl(ikn_own, rr, 64);
    float rs = 0.f;
#pragma unroll
    for (int tt = 0; tt < 8; ++tt) {
      float e = __expf(accT[tt][q] * imn[tt] * zb);
      accT[tt][q] = e;
      rs += e;
    }
    rs += __shfl_xor(rs, 1, 64);
    rs += __shfl_xor(rs, 2, 64);
    rs += __shfl_xor(rs, 4, 64);
    rs += __shfl_xor(rs, 8, 64);
    if (l15 == 0) red[rr][w] = rs;
  }
  __syncthreads();

#pragma unroll
  for (int q = 0; q < 4; ++q) {
    const int rr = lg * 4 + q;
    float4 p0 = *(const float4*)&red[rr][0];
    float4 p1 = *(const float4*)&red[rr][4];
    float4 p2 = *(const float4*)&red[rr][8];
    float4 p3 = *(const float4*)&red[rr][12];
    float tot = (p0.x + p0.y + p0.z + p0.w) + (p1.x + p1.y + p1.z + p1.w) +
                (p2.x + p2.y + p2.z + p2.w) + (p3.x + p3.y + p3.z + p3.w);
    const float gv = 1.0f / (1.0f + __expf(-g_[b0 + rr]));
    const float ge = gv / tot;
    const float om = 1.0f - gv;
    const size_t rbase = (size_t)(b0 + rr) * NN + 128 * w + l15;
#pragma unroll
    for (int tt = 0; tt < 8; ++tt) {
      float wpv = w_prev[rbase + 16 * tt];
      accT[tt][q] = ge * accT[tt][q] + om * wpv;
    }
    if (l15 == 0) edges[rr][w][0] = accT[0][q];
    if (l15 == 15) edges[rr][w][1] = accT[7][q];
  }
  __syncthreads();

  const int tm = (lane & 48) | ((lane + 15) & 15);
  const int tp = (lane & 48) | ((lane + 1) & 15);
#pragma unroll
  for (int q = 0; q < 4; ++q) {
    const int rr = lg * 4 + q;
    float sh0 = s_[3 * (b0 + rr)];
    float sh1 = s_[3 * (b0 + rr) + 1];
    float sh2 = s_[3 * (b0 + rr) + 2];
    float shm = fmaxf(sh0, fmaxf(sh1, sh2));
    float e0 = __expf(sh0 - shm), e1 = __expf(sh1 - shm), e2 = __expf(sh2 - shm);
    float sden = 1.0f / (e0 + e1 + e2);
    sh0 = e0 * sden; sh1 = e1 * sden; sh2 = e2 * sden;
    const float gammav = 1.0f + softplusf(gamma_[b0 + rr]);
    const float eL = edges[rr][(w + 15) & 15][1];
    const float eR = edges[rr][(w + 1) & 15][0];
    float sm[8], sp[8];
#pragma unroll
    for (int tt = 0; tt < 8; ++tt) {
      sm[tt] = __shfl(accT[tt][q], tm, 64);
      sp[tt] = __shfl(accT[tt][q], tp, 64);
    }
    float rs = 0.f;
#pragma unroll
    for (int tt = 0; tt < 8; ++tt) {
      float pv = (l15 == 0) ? ((tt == 0) ? eL : sm[tt - 1]) : sm[tt];
      float nx = (l15 == 15) ? ((tt == 7) ? eR : sp[tt + 1]) : sp[tt];
      float wt = sh0 * pv + sh1 * accT[tt][q] + sh2 * nx;
      float p = __expf(gammav * __logf(wt));
      accT[tt][q] = p;
      rs += p;
    }
    rs += __shfl_xor(rs, 1, 64);
    rs += __shfl_xor(rs, 2, 64);
    rs += __shfl_xor(rs, 4, 64);
    rs += __shfl_xor(rs, 8, 64);
    if (l15 == 0) red[rr][w] = rs;
  }
  __syncthreads();

#pragma unroll
  for (int q = 0; q < 4; ++q) {
    const int rr = lg * 4 + q;
    float4 p0 = *(const float4*)&red[rr][0];
    float4 p1 = *(const float4*)&red[rr][4];
    float4 p2 = *(const float4*)&red[rr][8];
    float4 p3 = *(const float4*)&red[rr][12];
    float tot = (p0.x + p0.y + p0.z + p0.w) + (p1.x + p1.y + p1.z + p1.w) +
                (p2.x + p2.y + p2.z + p2.w) + (p3.x + p3.y + p3.z + p3.w);
    const float pinv = 1.0f / (tot + EPSF);
    const size_t rbase = (size_t)(b0 + rr) * NN + 128 * w + l15;
#pragma unroll
    for (int tt = 0; tt < 8; ++tt) {
      out[rbase + 16 * tt] = accT[tt][q] * pinv;
    }
  }
}

extern "C" void kernel_launch(void* const* d_in, const int* in_sizes, int n_in,
                              void* d_out, int out_size, void* d_ws, size_t ws_size,
                              hipStream_t stream) {
  const float* k = (const float*)d_in[0];
  const float* beta = (const float*)d_in[1];
  const float* g = (const float*)d_in[2];
  const float* s = (const float*)d_in[3];
  const float* gamma = (const float*)d_in[4];
  const float* w_prev = (const float*)d_in[5];
  const float* M = (const float*)d_in[6];
  float* out = (float*)d_out;

  // workspace layout (bytes)
  char* ws = (char*)d_ws;
  bf16x8* Mhf = (bf16x8*)(ws + 0);        // 512 KB (128 grp * 4 ks * 64 ln)
  bf16x8* Mlf = (bf16x8*)(ws + 524288);   // 512 KB
  bf16x8* Khf = (bf16x8*)(ws + 1048576);  // 1 MB (256 grp)
  bf16x8* Klf = (bf16x8*)(ws + 2097152);  // 1 MB
  float* imn = (float*)(ws + 3145728);    // 2048
  float* zb = imn + 2048;                 // 4096
  float* gvv = zb + 4096;
  float* gmv = gvv + 4096;
  float* s0a = gmv + 4096;
  float* s1a = s0a + 4096;
  float* s2a = s1a + 4096;
  const size_t need = 3145728 + 2048 * 4 + 6 * 4096 * 4;

  if (ws_size >= need) {
    ntm_prep_kernel<<<112, 256, 0, stream>>>(k, beta, g, s, gamma, M, Mhf, Mlf,
                                             Khf, Klf, imn, zb, gvv, gmv, s0a,
                                             s1a, s2a);
    ntm_main_kernel<<<4096 / ROWS, 1024, 0, stream>>>(
        w_prev, Mhf, Mlf, Khf, Klf, imn, zb, gvv, gmv, s0a, s1a, s2a, out);
  } else {
    ntm_main_fallback<<<4096 / ROWS, 1024, 0, stream>>>(k, beta, g, s, gamma,
                                                        w_prev, M, out);
  }
}